// Round 1
// baseline (491.684 us; speedup 1.0000x reference)
//
#include <hip/hip_runtime.h>

// Problem shape (fixed by reference): X [B, N, D] fp32, mask [B, N] int, W [D], b [D].
// B=64, N=8192, D=128.  REPLACE = 0.0 -> masked rows output b[d].
#define B_ 64
#define N_ 8192
#define D_ 128
#define D4 (D_ / 4)          // 32 float4 per row
#define NCHUNKS 16
#define CHUNK (N_ / NCHUNKS) // 512 rows per reduce block

// Workspace layout (floats):
//  [0, B*D)            sum
//  [B*D, 2*B*D)        sumsq
//  [2*B*D, 2*B*D+B)    count
//  [2*B*D+B, 3*B*D+B)  scale
//  [3*B*D+B, 4*B*D+B)  shift
#define WS_SUM    0
#define WS_SUMSQ  (B_ * D_)
#define WS_COUNT  (2 * B_ * D_)
#define WS_SCALE  (2 * B_ * D_ + B_)
#define WS_SHIFT  (3 * B_ * D_ + B_)
#define WS_ZERO_N (2 * B_ * D_ + B_)   // elements that must start at 0

__global__ __launch_bounds__(256) void init_ws(float* __restrict__ ws) {
    int i = blockIdx.x * blockDim.x + threadIdx.x;
    if (i < WS_ZERO_N) ws[i] = 0.0f;
}

__global__ __launch_bounds__(256) void reduce_kernel(
        const float* __restrict__ X, const int* __restrict__ mask,
        float* __restrict__ ws) {
    float* __restrict__ sum   = ws + WS_SUM;
    float* __restrict__ sumsq = ws + WS_SUMSQ;
    float* __restrict__ count = ws + WS_COUNT;

    const int b   = blockIdx.x;
    const int n0  = blockIdx.y * CHUNK;
    const int tid = threadIdx.x;
    const int q   = tid & 31;   // float4 column within row
    const int sub = tid >> 5;   // 0..7 row phase

    const float4* __restrict__ Xr = (const float4*)(X + (size_t)b * N_ * D_);
    const int*    __restrict__ mr = mask + b * N_;

    float4 s  = make_float4(0.f, 0.f, 0.f, 0.f);
    float4 ss = make_float4(0.f, 0.f, 0.f, 0.f);
    float  cnt = 0.f;

    for (int n = n0 + sub; n < n0 + CHUNK; n += 8) {
        if (mr[n] == 0) {                    // valid (mask==True means masked OUT)
            float4 x = Xr[(size_t)n * D4 + q];
            s.x += x.x;  s.y += x.y;  s.z += x.z;  s.w += x.w;
            ss.x += x.x * x.x;  ss.y += x.y * x.y;
            ss.z += x.z * x.z;  ss.w += x.w * x.w;
            if (q == 0) cnt += 1.f;
        }
    }

    __shared__ float4 sh_s[8][32];
    __shared__ float4 sh_ss[8][32];
    __shared__ float  sh_c[8];
    sh_s[sub][q]  = s;
    sh_ss[sub][q] = ss;
    if (q == 0) sh_c[sub] = cnt;
    __syncthreads();

    if (sub == 0) {
        float4 ts = s, tss = ss;
        for (int k = 1; k < 8; ++k) {
            float4 a = sh_s[k][q], bb = sh_ss[k][q];
            ts.x += a.x;  ts.y += a.y;  ts.z += a.z;  ts.w += a.w;
            tss.x += bb.x; tss.y += bb.y; tss.z += bb.z; tss.w += bb.w;
        }
        const int base = b * D_ + q * 4;
        atomicAdd(&sum[base + 0], ts.x);
        atomicAdd(&sum[base + 1], ts.y);
        atomicAdd(&sum[base + 2], ts.z);
        atomicAdd(&sum[base + 3], ts.w);
        atomicAdd(&sumsq[base + 0], tss.x);
        atomicAdd(&sumsq[base + 1], tss.y);
        atomicAdd(&sumsq[base + 2], tss.z);
        atomicAdd(&sumsq[base + 3], tss.w);
    }
    if (tid == 0) {
        float c = 0.f;
        for (int k = 0; k < 8; ++k) c += sh_c[k];
        atomicAdd(&count[b], c);
    }
}

__global__ __launch_bounds__(256) void finalize_kernel(
        const float* __restrict__ W, const float* __restrict__ bias,
        float* __restrict__ ws) {
    const float* __restrict__ sum   = ws + WS_SUM;
    const float* __restrict__ sumsq = ws + WS_SUMSQ;
    const float* __restrict__ count = ws + WS_COUNT;
    float* __restrict__ scale = ws + WS_SCALE;
    float* __restrict__ shift = ws + WS_SHIFT;

    int i = blockIdx.x * blockDim.x + threadIdx.x;   // 0 .. B*D
    if (i >= B_ * D_) return;
    int b = i >> 7;        // / D_
    int d = i & (D_ - 1);
    float c    = count[b];
    float s    = sum[i];
    float sq   = sumsq[i];
    float mean = s / c;
    // unbiased: var = (sumsq - sum*mean) / (c - 1)
    float var  = (sq - s * mean) / (c - 1.0f);
    float inv  = rsqrtf(var);
    float sc   = W[d] * inv;
    scale[i] = sc;
    shift[i] = bias[d] - mean * sc;
}

__global__ __launch_bounds__(256) void normalize_kernel(
        const float* __restrict__ X, const int* __restrict__ mask,
        const float* __restrict__ ws, const float* __restrict__ bias,
        float* __restrict__ out) {
    const float4* __restrict__ X4 = (const float4*)X;
    float4* __restrict__ O4 = (float4*)out;
    const float4* __restrict__ S4 = (const float4*)(ws + WS_SCALE);
    const float4* __restrict__ H4 = (const float4*)(ws + WS_SHIFT);
    const float4* __restrict__ B4 = (const float4*)bias;

    const long long total = (long long)B_ * N_ * D4;   // float4 elements
    long long i = (long long)blockIdx.x * blockDim.x + threadIdx.x;
    const long long stride = (long long)gridDim.x * blockDim.x;

    for (; i < total; i += stride) {
        int row = (int)(i >> 5);        // / D4
        int c   = (int)(i & 31);
        int b   = row >> 13;            // / N_
        float4 o;
        if (mask[row] != 0) {
            o = B4[c];                  // REPLACE(=0)*W + b  ->  b
        } else {
            float4 x  = X4[i];
            float4 sc = S4[b * D4 + c];
            float4 sh = H4[b * D4 + c];
            o.x = x.x * sc.x + sh.x;
            o.y = x.y * sc.y + sh.y;
            o.z = x.z * sc.z + sh.z;
            o.w = x.w * sc.w + sh.w;
        }
        O4[i] = o;
    }
}

extern "C" void kernel_launch(void* const* d_in, const int* in_sizes, int n_in,
                              void* d_out, int out_size, void* d_ws, size_t ws_size,
                              hipStream_t stream) {
    const float* X    = (const float*)d_in[0];
    const int*   mask = (const int*)d_in[1];
    const float* W    = (const float*)d_in[2];
    const float* bias = (const float*)d_in[3];
    float* out = (float*)d_out;
    float* ws  = (float*)d_ws;

    // 1) zero the accumulator region of the workspace (harness poisons it)
    init_ws<<<(WS_ZERO_N + 255) / 256, 256, 0, stream>>>(ws);

    // 2) per-(batch, chunk) partial reduction of sum / sumsq / count
    reduce_kernel<<<dim3(B_, NCHUNKS), 256, 0, stream>>>(X, mask, ws);

    // 3) mean/var -> scale/shift
    finalize_kernel<<<(B_ * D_ + 255) / 256, 256, 0, stream>>>(W, bias, ws);

    // 4) elementwise normalize + affine + mask-replace
    normalize_kernel<<<4096, 256, 0, stream>>>(X, mask, ws, bias, out);
}